// Round 20
// baseline (182.373 us; speedup 1.0000x reference)
//
#include <hip/hip_runtime.h>
#include <hip/hip_bf16.h>

// Problem constants
#define B_ 2
#define S_ 2048
#define D_ 1024
#define H_ 16
#define P_ 2048
#define T_ 4096   // P_ + S_
#define DEPTH_ 64

typedef __bf16 bf16x8 __attribute__((ext_vector_type(8)));
typedef float  f32x4  __attribute__((ext_vector_type(4)));
typedef short  short8_t __attribute__((ext_vector_type(8)));
typedef unsigned short ushort_t;
typedef unsigned short ushort4_t __attribute__((ext_vector_type(4)));

// f32 -> bf16 round-to-nearest-even (cold paths)
__device__ __forceinline__ ushort_t f2bf(float f) {
    union { float f; unsigned u; } v; v.f = f;
    return (ushort_t)((v.u + 0x7fffu + ((v.u >> 16) & 1u)) >> 16);
}

// packed pair f32 -> 2x bf16 in one u32 (hot path; no builtin on gfx950)
__device__ __forceinline__ unsigned cvt_pk_bf16(float lo, float hi) {
    unsigned r;
    asm("v_cvt_pk_bf16_f32 %0, %1, %2" : "=v"(r) : "v"(lo), "v"(hi));
    return r;
}

__device__ __forceinline__ void gload16(const void* g, void* l) {
    __builtin_amdgcn_global_load_lds(
        (const __attribute__((address_space(1))) unsigned int*)g,
        (__attribute__((address_space(3))) unsigned int*)l, 16, 0, 0);
}

// =====================================================================
// Fused input prep, one launch:
//   blocks [0,2048):    x [4096][1024] f32 -> bf16 (2 float4/thread)
//   blocks [2048,2816): w_attn [1024][3072] -> wta [3072][1024] bf16
//   blocks [2816,3072): w_proj [1024][1024] -> wtp [1024][1024] bf16
// =====================================================================
__global__ __launch_bounds__(256)
void prep_inputs_kernel(const float4* __restrict__ x, ushort4_t* __restrict__ xb,
                        const float* __restrict__ wa, ushort_t* __restrict__ wta,
                        const float* __restrict__ wp, ushort_t* __restrict__ wtp)
{
    __shared__ float t[64][65];
    const int bid = (int)blockIdx.x;
    const int tid = threadIdx.x;

    if (bid < 2048) {
        const int base = bid * 512 + tid;
        #pragma unroll
        for (int r = 0; r < 2; ++r) {
            float4 v = x[base + r*256];
            ushort4_t o;
            o[0] = f2bf(v.x); o[1] = f2bf(v.y); o[2] = f2bf(v.z); o[3] = f2bf(v.w);
            xb[base + r*256] = o;
        }
        return;
    }

    const int p = bid - 2048;
    const bool isA = (p < 768);
    const float* w = isA ? wa : wp;
    ushort_t* wt  = isA ? wta : wtp;
    const int N   = isA ? 3072 : 1024;
    const int pp  = isA ? p : (p - 768);
    const int nb  = isA ? 48 : 16;
    const int n0  = (pp % nb) * 64;
    const int k0  = (pp / nb) * 64;

    #pragma unroll
    for (int rep = 0; rep < 4; ++rep) {
        const int idx = rep * 256 + tid;
        const int r = idx >> 4, c = idx & 15;
        float4 v = *(const float4*)&w[(size_t)(k0 + r) * N + n0 + c * 4];
        t[r][c*4+0] = v.x; t[r][c*4+1] = v.y; t[r][c*4+2] = v.z; t[r][c*4+3] = v.w;
    }
    __syncthreads();
    #pragma unroll
    for (int rep = 0; rep < 4; ++rep) {
        const int idx = rep * 256 + tid;
        const int nl = idx >> 4, kg = idx & 15;
        ushort4_t o;
        o[0] = f2bf(t[kg*4+0][nl]); o[1] = f2bf(t[kg*4+1][nl]);
        o[2] = f2bf(t[kg*4+2][nl]); o[3] = f2bf(t[kg*4+3][nl]);
        *(ushort4_t*)&wt[(size_t)(n0 + nl) * 1024 + k0 + kg*4] = o;
    }
}

// =====================================================================
// Fused: QKV GEMM (blocks 0..767) + past->present/K_ws/V_ws old rows
// (blocks 768..1791).
// =====================================================================
__global__ __launch_bounds__(256)
void gemm0_prep_kernel(const ushort_t* __restrict__ A,
                       const ushort_t* __restrict__ Bt,
                       const float*  __restrict__ bias,
                       ushort_t* __restrict__ out_qb,
                       float*  __restrict__ out_present,
                       ushort_t* __restrict__ out_kws,
                       ushort_t* __restrict__ out_vws,
                       const float* __restrict__ past)
{
    __shared__ __attribute__((aligned(16))) float tvf[64][65];   // 16,640 B union

    const int bid = (int)blockIdx.x;
    const int tid = threadIdx.x;

    if (bid >= 768) {
        // ---------------- prep_kv_old path ----------------
        const int pid = bid - 768;
        const int kt  = pid & 31;
        const int bh  = pid >> 5;
        const int b   = bh >> 4, h = bh & 15;

        const float* Kp = past + (((size_t)(b*2+0)*16 + h) * P_ + kt*64) * 64;
        const float* Vp = past + (((size_t)(b*2+1)*16 + h) * P_ + kt*64) * 64;
        float4* PKo = (float4*)(out_present + (((size_t)(b*2+0)*16 + h) * T_ + kt*64) * 64);
        float4* PVo = (float4*)(out_present + (((size_t)(b*2+1)*16 + h) * T_ + kt*64) * 64);
        ushort_t* Kd = out_kws + ((size_t)bh * T_ + kt*64) * 64;

        #pragma unroll
        for (int rep = 0; rep < 4; ++rep) {
            const int idx = rep * 256 + tid;
            float4 v = ((const float4*)Kp)[idx];
            PKo[idx] = v;
            ushort4_t o;
            o[0] = f2bf(v.x); o[1] = f2bf(v.y); o[2] = f2bf(v.z); o[3] = f2bf(v.w);
            *(ushort4_t*)&Kd[idx*4] = o;
            float4 vv = ((const float4*)Vp)[idx];
            PVo[idx] = vv;
            const int r = idx >> 4, c = idx & 15;
            tvf[r][c*4+0] = vv.x; tvf[r][c*4+1] = vv.y;
            tvf[r][c*4+2] = vv.z; tvf[r][c*4+3] = vv.w;
        }
        __syncthreads();
        #pragma unroll
        for (int rep = 0; rep < 4; ++rep) {
            const int idx = rep * 256 + tid;
            const int d = idx >> 4, pg = idx & 15;
            ushort4_t o;
            o[0] = f2bf(tvf[pg*4+0][d]); o[1] = f2bf(tvf[pg*4+1][d]);
            o[2] = f2bf(tvf[pg*4+2][d]); o[3] = f2bf(tvf[pg*4+3][d]);
            *(ushort4_t*)&out_vws[((size_t)bh*64 + d) * T_ + kt*64 + pg*4] = o;
        }
        return;
    }

    // ---------------- gemm0 path (QKV projection) ----------------
    ushort_t* As = (ushort_t*)tvf;
    ushort_t* Bs = (ushort_t*)tvf + 4096;

    const int w    = tid >> 6;
    const int lane = tid & 63;
    const int g    = lane >> 4;
    const int ln   = lane & 15;
    const int wr   = w >> 1, wc = w & 1;
    const int row0 = (bid / 24) * 128;
    const int col0 = (bid % 24) * 128;

    int srow[2], sgl[2];
    #pragma unroll
    for (int r = 0; r < 2; ++r) {
        const int o = (w*2 + r) * 1024 + lane * 16;
        srow[r] = o >> 6;
        const int gp = (o >> 4) & 3;
        sgl[r] = gp ^ ((srow[r] >> 1) & 3);
    }

    f32x4 acc[4][4];
    #pragma unroll
    for (int i = 0; i < 4; ++i)
        #pragma unroll
        for (int j = 0; j < 4; ++j)
            acc[i][j] = (f32x4){0.f, 0.f, 0.f, 0.f};

    for (int k0 = 0; k0 < 1024; k0 += 32) {
        #pragma unroll
        for (int r = 0; r < 2; ++r) {
            const int lb = (w*2 + r) * 512;
            gload16(&A [(size_t)(row0 + srow[r]) * 1024 + k0 + sgl[r]*8], &As[lb]);
            gload16(&Bt[(size_t)(col0 + srow[r]) * 1024 + k0 + sgl[r]*8], &Bs[lb]);
        }
        __syncthreads();

        bf16x8 af[4], bfr[4];
        #pragma unroll
        for (int i = 0; i < 4; ++i) {
            const int ra = wr*64 + i*16 + ln;
            const int ga = g ^ ((ra >> 1) & 3);
            af[i] = __builtin_bit_cast(bf16x8, *(const short8_t*)&As[ra*32 + ga*8]);
            const int rb = wc*64 + i*16 + ln;
            const int gb = g ^ ((rb >> 1) & 3);
            bfr[i] = __builtin_bit_cast(bf16x8, *(const short8_t*)&Bs[rb*32 + gb*8]);
        }
        #pragma unroll
        for (int i = 0; i < 4; ++i)
            #pragma unroll
            for (int j = 0; j < 4; ++j)
                acc[i][j] = __builtin_amdgcn_mfma_f32_16x16x32_bf16(af[i], bfr[j], acc[i][j], 0, 0, 0);
        __syncthreads();
    }

    #pragma unroll
    for (int i = 0; i < 4; ++i) {
        const int rm0 = row0 + wr*64 + i*16 + g*4;
        const int b   = rm0 >> 11;
        const int s0  = rm0 & 2047;
        #pragma unroll
        for (int jn = 0; jn < 4; ++jn) {
            const int e = col0 + wc*64 + jn*16 + ln;
            float vv[4];
            #pragma unroll
            for (int j = 0; j < 4; ++j) vv[j] = acc[i][jn][j] + bias[e];
            const int which = e >> 10;
            const int f = e & 1023;
            const int h = f >> 6, d = f & 63;
            const int bh = b*16 + h;
            if (which == 0) {
                #pragma unroll
                for (int j = 0; j < 4; ++j)
                    out_qb[(size_t)(((bh) * 2048 + s0 + j) << 6) + d] =
                        f2bf(vv[j] * 0.18033688f);
            } else if (which == 1) {
                #pragma unroll
                for (int j = 0; j < 4; ++j) {
                    out_present[((((size_t)(b*2)*16 + h) * 4096 + 2048 + s0 + j) << 6) + d] = vv[j];
                    out_kws[(((size_t)bh * T_ + 2048 + s0 + j) << 6) + d] = f2bf(vv[j]);
                }
            } else {
                ushort4_t pk;
                #pragma unroll
                for (int j = 0; j < 4; ++j) {
                    out_present[((((size_t)(b*2 + 1)*16 + h) * 4096 + 2048 + s0 + j) << 6) + d] = vv[j];
                    pk[j] = f2bf(vv[j]);
                }
                *(ushort4_t*)&out_vws[((size_t)bh*64 + d) * T_ + 2048 + s0] = pk;
            }
        }
    }
}

// =====================================================================
// bf16 MFMA GEMM (m97 structure) — output projection only.
// =====================================================================
__global__ __launch_bounds__(256)
void gemm_proj_kernel(const ushort_t* __restrict__ A,
                      const ushort_t* __restrict__ Bt,
                      const float*  __restrict__ bias,
                      float*  __restrict__ out_plain)
{
    __shared__ __attribute__((aligned(16))) ushort_t As[128*32];
    __shared__ __attribute__((aligned(16))) ushort_t Bs[128*32];

    const int tid  = threadIdx.x;
    const int w    = tid >> 6;
    const int lane = tid & 63;
    const int g    = lane >> 4;
    const int ln   = lane & 15;
    const int wr   = w >> 1, wc = w & 1;
    const int row0 = blockIdx.y * 128;
    const int col0 = blockIdx.x * 128;

    int srow[2], sgl[2];
    #pragma unroll
    for (int r = 0; r < 2; ++r) {
        const int o = (w*2 + r) * 1024 + lane * 16;
        srow[r] = o >> 6;
        const int gp = (o >> 4) & 3;
        sgl[r] = gp ^ ((srow[r] >> 1) & 3);
    }

    f32x4 acc[4][4];
    #pragma unroll
    for (int i = 0; i < 4; ++i)
        #pragma unroll
        for (int j = 0; j < 4; ++j)
            acc[i][j] = (f32x4){0.f, 0.f, 0.f, 0.f};

    for (int k0 = 0; k0 < 1024; k0 += 32) {
        #pragma unroll
        for (int r = 0; r < 2; ++r) {
            const int lb = (w*2 + r) * 512;
            gload16(&A [(size_t)(row0 + srow[r]) * 1024 + k0 + sgl[r]*8], &As[lb]);
            gload16(&Bt[(size_t)(col0 + srow[r]) * 1024 + k0 + sgl[r]*8], &Bs[lb]);
        }
        __syncthreads();

        bf16x8 af[4], bfr[4];
        #pragma unroll
        for (int i = 0; i < 4; ++i) {
            const int ra = wr*64 + i*16 + ln;
            const int ga = g ^ ((ra >> 1) & 3);
            af[i] = __builtin_bit_cast(bf16x8, *(const short8_t*)&As[ra*32 + ga*8]);
            const int rb = wc*64 + i*16 + ln;
            const int gb = g ^ ((rb >> 1) & 3);
            bfr[i] = __builtin_bit_cast(bf16x8, *(const short8_t*)&Bs[rb*32 + gb*8]);
        }
        #pragma unroll
        for (int i = 0; i < 4; ++i)
            #pragma unroll
            for (int j = 0; j < 4; ++j)
                acc[i][j] = __builtin_amdgcn_mfma_f32_16x16x32_bf16(af[i], bfr[j], acc[i][j], 0, 0, 0);
        __syncthreads();
    }

    #pragma unroll
    for (int i = 0; i < 4; ++i) {
        #pragma unroll
        for (int j = 0; j < 4; ++j) {
            const int rm = row0 + wr*64 + i*16 + g*4 + j;
            #pragma unroll
            for (int jn = 0; jn < 4; ++jn) {
                const int e = col0 + wc*64 + jn*16 + ln;
                out_plain[(size_t)rm * 1024 + e] = acc[i][jn][j] + bias[e];
            }
        }
    }
}

// =====================================================================
// Flash attention v15 = v14 + deferred softmax (T15 att[2] pipeline):
// per tile t: QK(t)->STCUR, then exp(STPRV)+P-write(t-1)+PV(t-1).
// The exp chain (register-only, independent of QK(t)) fills QK's
// MFMA/ds_read latency. Two named score sets (stAr/stBr) alternate at
// compile time via the 4-unrolled loop (t even: cur=A, prev=B).
// nt always even => final tile's scores statically in stBr.
// P single-buffered (wave-private rows, same-wave LDS in-order).
// =====================================================================
__global__ __launch_bounds__(256, 2)
void attn_v15_kernel(const ushort_t* __restrict__ qin,   // [B,H,S,64] bf16 (pre-scaled, log2 domain)
                     const ushort_t* __restrict__ Kws,   // [bh][T][64] bf16
                     const ushort_t* __restrict__ Vws,   // [bh][64][T] bf16
                     ushort_t* __restrict__ merged)      // [B,S,D] bf16
{
    __shared__ __attribute__((aligned(16))) ushort_t Kb[2][4096];  // K tiles [64][64]
    __shared__ __attribute__((aligned(16))) ushort_t Vb[4][4096];  // V^T tiles [64 d][64 key]
    __shared__ __attribute__((aligned(16))) ushort_t Pb[128*64];   // P^T [128 q rows][64 keys]

    const int tid  = threadIdx.x;
    const int w    = tid >> 6;
    const int lane = tid & 63;
    const int g    = lane >> 4;
    const int ln   = lane & 15;
    const int lnm  = ln & 7;
    const int lsub = lane >> 3;
    const int swz8 = ((lane & 7) ^ lsub) * 8;

    const int bid = (int)blockIdx.x;
    const int a   = bid & 7;
    const int m_c = (bid >> 3) & 31;
    const int j   = bid >> 8;
    const int bh  = a * 4 + (m_c & 3);
    const int c   = m_c >> 2;
    const int qblk = (j == 0) ? c : (15 - c);
    const int q0   = qblk * 128;
    const int b    = bh >> 4, h = bh & 15;

    const ushort_t* Kbase = Kws + (size_t)bh * T_ * 64;
    const ushort_t* Vbase = Vws + (size_t)bh * 64 * T_;
    const int nt = 34 + 2 * qblk;   // always even

    const int kgOff0 = ((w*16 + 0 + lsub) << 6) + swz8;
    const int kgOff1 = ((w*16 + 8 + lsub) << 6) + swz8;
    const size_t vgOff0 = (size_t)(w*16 + 0 + lsub) * T_ + swz8;
    const size_t vgOff1 = (size_t)(w*16 + 8 + lsub) * T_ + swz8;
    const int ldsOff0 = (w*2 + 0) * 512;
    const int ldsOff1 = (w*2 + 1) * 512;
    const int pRow0 = (w*32 + ln) * 64;
    const int pRow1 = (w*32 + 16 + ln) * 64;

    gload16(Kbase + kgOff0, &Kb[0][ldsOff0]);
    gload16(Kbase + kgOff1, &Kb[0][ldsOff1]);
    gload16(Vbase + vgOff0, &Vb[0][ldsOff0]);
    gload16(Vbase + vgOff1, &Vb[0][ldsOff1]);
    gload16(Vbase + vgOff0 + 64, &Vb[1][ldsOff0]);
    gload16(Vbase + vgOff1 + 64, &Vb[1][ldsOff1]);

    bf16x8 qf[2][2];
    #pragma unroll
    for (int qg = 0; qg < 2; ++qg) {
        const ushort_t* Qr = qin + ((size_t)bh * S_ + q0 + w*32 + qg*16 + ln) * 64;
        #pragma unroll
        for (int kh = 0; kh < 2; ++kh)
            qf[qg][kh] = __builtin_bit_cast(bf16x8, *(const short8_t*)(Qr + kh*32 + g*8));
    }

    f32x4 o[2][4];
    #pragma unroll
    for (int qg = 0; qg < 2; ++qg)
        #pragma unroll
        for (int d = 0; d < 4; ++d) o[qg][d] = (f32x4){0.f, 0.f, 0.f, 0.f};
    float l0 = 0.f, l1 = 0.f;

    f32x4 stAr[2][4], stBr[2][4];   // double score state (T15)

    auto pv_step = [&](const ushort_t* vbase) {
        __builtin_amdgcn_s_setprio(1);
        #pragma unroll
        for (int kh = 0; kh < 2; ++kh) {
            bf16x8 pf0 = __builtin_bit_cast(bf16x8,
                           *(const short8_t*)&Pb[pRow0 + (((kh*4 + g) ^ lnm) << 3)]);
            bf16x8 pf1 = __builtin_bit_cast(bf16x8,
                           *(const short8_t*)&Pb[pRow1 + (((kh*4 + g) ^ lnm) << 3)]);
            #pragma unroll
            for (int dsub = 0; dsub < 4; ++dsub) {
                const ushort_t* vr = vbase + (dsub*16 + ln) * 64;
                bf16x8 va = __builtin_bit_cast(bf16x8,
                              *(const short8_t*)(vr + ((kh*4 + g) ^ lnm)*8));
                o[0][dsub] = __builtin_amdgcn_mfma_f32_16x16x32_bf16(va, pf0, o[0][dsub], 0, 0, 0);
                o[1][dsub] = __builtin_amdgcn_mfma_f32_16x16x32_bf16(va, pf1, o[1][dsub], 0, 0, 0);
            }
        }
        __builtin_amdgcn_s_setprio(0);
    };

#define EXP_WRITE(ST)                                                           \
    _Pragma("unroll")                                                           \
    for (int qg = 0; qg < 2; ++qg) {                                            \
        const int pR = qg ? pRow1 : pRow0;                                      \
        float rs = 0.f;                                                         \
        _Pragma("unroll")                                                       \
        for (int js = 0; js < 4; ++js) {                                        \
            float p0 = exp2f(ST[qg][js][0]);                                    \
            float p1 = exp2f(ST[qg][js][1]);                                    \
            float p2 = exp2f(ST[qg][js][2]);                                    \
            float p3 = exp2f(ST[qg][js][3]);                                    \
            rs += (p0 + p1) + (p2 + p3);                                        \
            uint2 pk;                                                           \
            pk.x = cvt_pk_bf16(p0, p1);                                         \
            pk.y = cvt_pk_bf16(p2, p3);                                         \
            *(uint2*)&Pb[pR + (((js*4 + g) ^ (lnm << 1)) << 2)] = pk;           \
        }                                                                       \
        if (qg) l1 += rs; else l0 += rs;                                        \
    }

#define ATTN_STEP(KCUR, KNXT, VPRV, VISS, STCUR, STPRV)                         \
    {                                                                           \
        if (t + 1 < nt) { asm volatile("s_waitcnt vmcnt(2)" ::: "memory"); }    \
        else            { asm volatile("s_waitcnt vmcnt(0)" ::: "memory"); }    \
        __builtin_amdgcn_s_barrier();                                           \
        __builtin_amdgcn_sched_barrier(0);                                      \
        if (t + 1 < nt) {                                                       \
            const size_t t0n = (size_t)(t + 1) * 64;                            \
            gload16(Kbase + (t0n << 6) + kgOff0, &Kb[KNXT][ldsOff0]);           \
            gload16(Kbase + (t0n << 6) + kgOff1, &Kb[KNXT][ldsOff1]);           \
        }                                                                       \
        if (t + 2 < nt) {                                                       \
            const size_t t0v = (size_t)(t + 2) * 64;                            \
            gload16(Vbase + vgOff0 + t0v, &Vb[VISS][ldsOff0]);                  \
            gload16(Vbase + vgOff1 + t0v, &Vb[VISS][ldsOff1]);                  \
        }                                                                       \
        __builtin_amdgcn_sched_barrier(0);                                      \
        __builtin_amdgcn_s_setprio(1);                                          \
        _Pragma("unroll")                                                       \
        for (int js = 0; js < 4; ++js) {                                        \
            const ushort_t* kr = &Kb[KCUR][(js*16 + ln) * 64];                  \
            bf16x8 a0 = __builtin_bit_cast(bf16x8, *(const short8_t*)(kr + ((    g) ^ lnm)*8)); \
            bf16x8 a1 = __builtin_bit_cast(bf16x8, *(const short8_t*)(kr + ((4 + g) ^ lnm)*8)); \
            _Pragma("unroll")                                                   \
            for (int qg = 0; qg < 2; ++qg) {                                    \
                f32x4 z = (f32x4){0.f, 0.f, 0.f, 0.f};                          \
                z = __builtin_amdgcn_mfma_f32_16x16x32_bf16(a0, qf[qg][0], z, 0, 0, 0); \
                z = __builtin_amdgcn_mfma_f32_16x16x32_bf16(a1, qf[qg][1], z, 0, 0, 0); \
                STCUR[qg][js] = z;                                              \
            }                                                                   \
        }                                                                       \
        __builtin_amdgcn_s_setprio(0);                                          \
        if (t >= nt - 2) {  /* mask current tile's scores */                    \
            const int off = t*64 - 2048 - q0;                                   \
            _Pragma("unroll")                                                   \
            for (int qg = 0; qg < 2; ++qg) {                                    \
                const int wrow = w*32 + qg*16 + ln;                             \
                _Pragma("unroll")                                               \
                for (int js = 0; js < 4; ++js)                                  \
                    _Pragma("unroll")                                           \
                    for (int r = 0; r < 4; ++r)                                 \
                        if (js*16 + g*4 + r + off > wrow) STCUR[qg][js][r] = -1e30f; \
            }                                                                   \
        }                                                                       \
        if (t > 0) {        /* deferred: softmax + PV of tile t-1 */            \
            EXP_WRITE(STPRV);                                                   \
            pv_step(&Vb[VPRV][0]);                                              \
        }                                                                       \
    }

    int t = 0;
    for (;;) {
        ATTN_STEP(0, 1, 3, 2, stAr, stBr);   // t%4==0
        if (++t == nt) break;
        ATTN_STEP(1, 0, 0, 3, stBr, stAr);   // t%4==1
        if (++t == nt) break;
        ATTN_STEP(0, 1, 1, 0, stAr, stBr);   // t%4==2
        if (++t == nt) break;
        ATTN_STEP(1, 0, 2, 1, stBr, stAr);   // t%4==3
        if (++t == nt) break;
    }
#undef ATTN_STEP

    // ---- drain: final tile's softmax + PV (nt even => scores in stBr) ----
    EXP_WRITE(stBr);
    pv_step(&Vb[(nt - 1) & 3][0]);
#undef EXP_WRITE

    float lf0 = l0 + __shfl_xor(l0, 16); lf0 += __shfl_xor(lf0, 32);
    float lf1 = l1 + __shfl_xor(l1, 16); lf1 += __shfl_xor(lf1, 32);
    #pragma unroll
    for (int qg = 0; qg < 2; ++qg) {
        const float inv = 1.f / (qg ? lf1 : lf0);
        const int row = q0 + w*32 + qg*16 + ln;
        #pragma unroll
        for (int dsub = 0; dsub < 4; ++dsub) {
            ushort4_t ov;
            ov[0] = f2bf(o[qg][dsub][0] * inv);
            ov[1] = f2bf(o[qg][dsub][1] * inv);
            ov[2] = f2bf(o[qg][dsub][2] * inv);
            ov[3] = f2bf(o[qg][dsub][3] * inv);
            *(ushort4_t*)&merged[((size_t)b * S_ + row) * D_ + h*64 + dsub*16 + g*4] = ov;
        }
    }
}

// =====================================================================
extern "C" void kernel_launch(void* const* d_in, const int* in_sizes, int n_in,
                              void* d_out, int out_size, void* d_ws, size_t ws_size,
                              hipStream_t stream)
{
    const float* x      = (const float*)d_in[0];
    // d_in[1] = mask: causal structure computed analytically, never read
    const float* past   = (const float*)d_in[2];
    const float* w_attn = (const float*)d_in[3];
    const float* b_attn = (const float*)d_in[4];
    const float* w_proj = (const float*)d_in[5];
    const float* b_proj = (const float*)d_in[6];

    float* out     = (float*)d_out;                    // [B,S,D]
    float* present = out + (size_t)B_ * S_ * D_;       // [B,2,H,T,64]

    // ws layout (ushorts)
    ushort_t* wsu     = (ushort_t*)d_ws;
    ushort_t* q_ws    = wsu;                  // [B,H,S,64]   8 MB
    ushort_t* mergedb = wsu + 4194304;        // [4096][1024] 8 MB
    ushort_t* wptb    = wsu + 8388608;        // [1024][1024] 2 MB
    ushort_t* xb      = wsu + 9437184;        // [4096][1024] 8 MB
    ushort_t* watb    = wsu + 13631488;       // [3072][1024] 6 MB
    ushort_t* K_ws    = wsu + 16777216;       // [32][T][64] 16 MB
    ushort_t* V_ws    = wsu + 25165824;       // [32][64][T] 16 MB

    // 0) fused input prep: convert x + transpose both weights
    prep_inputs_kernel<<<dim3(3072), 256, 0, stream>>>(
        (const float4*)x, (ushort4_t*)xb, w_attn, watb, w_proj, wptb);

    // 1) fused: QKV GEMM (new rows) + past->present/K_ws/V_ws (old rows)
    gemm0_prep_kernel<<<dim3(1792), 256, 0, stream>>>(
        xb, watb, b_attn, q_ws, present, K_ws, V_ws, past);

    // 2) flash attention v15 (deferred softmax pipeline) -> merged bf16
    attn_v15_kernel<<<dim3(512), 256, 0, stream>>>(q_ws, K_ws, V_ws, mergedb);

    // 3) output projection
    gemm_proj_kernel<<<dim3(8, 32), 256, 0, stream>>>(
        mergedb, wptb, b_proj, out);
}